// Round 10
// baseline (157.639 us; speedup 1.0000x reference)
//
#include <hip/hip_runtime.h>
#include <math.h>

// B=2, N=2048, C=384, H=6, D=64.  All quantized tensors hold INTEGER values
// (round(clip(x/a))) stored as int8; alpha scales are factored into epilogues.
// All GEMMs use v_mfma_i32_16x16x64_i8 (i32 accumulation exact; sums < 2^24
// so the (float) conversion is bit-exact).
//
// Round 10:
//  - attn_fused phase C restructured for ILP: vals for all 4 rows read first,
//    4 max chains interleaved, all 16 E2 slice loads issued together into
//    registers (global latency overlapped once, not 4x serialized), then the
//    per-row LDS stage/gather/sum/translate runs with per-row op order
//    unchanged (l bit-identical).  __launch_bounds__(256,4) pins VGPR<=128.
//  - qclip via v_med3_f32 (median == clamp for finite x, bit-identical).
//  - gemm_proj retiled with the gemm_qkv K-split structure (2-way K x 2-way
//    N waves + exact int LDS reduce).

typedef int i32x4 __attribute__((ext_vector_type(4)));
typedef float f32x2 __attribute__((ext_vector_type(2)));

#define MFMA_I8(a, b, c) __builtin_amdgcn_mfma_i32_16x16x64_i8(a, b, c, 0, 0, 0)

__device__ __forceinline__ float qclip(float s) {
  return __builtin_amdgcn_fmed3f(s, -128.0f, 127.0f);
}

// Markstein divide: with rc = RN(1/c) (IEEE), result == RN(x/c) for all
// normal inputs -> bit-identical to the / operator.
__device__ __forceinline__ float fdivn(float x, float c, float rc) {
  float q0 = x * rc;
  float e = fmaf(-c, q0, x);
  return fmaf(e, rc, q0);
}

// Packed pair version: identical per-lane ops/order -> bit-identical.
__device__ __forceinline__ f32x2 fdivn2(f32x2 x, f32x2 c, f32x2 rc) {
  f32x2 q0 = x * rc;
  f32x2 e = __builtin_elementwise_fma(-c, q0, x);
  return __builtin_elementwise_fma(e, rc, q0);
}

__device__ __forceinline__ void quant16_body(const float* __restrict__ in,
                                             signed char* __restrict__ out,
                                             float a, int i) {
  const float ra = 1.0f / a;
  const float4* p = (const float4*)in + 4 * (size_t)i;
  union { uint4 u; signed char c[16]; } o;
#pragma unroll
  for (int u = 0; u < 4; ++u) {
    float4 v = p[u];
    o.c[4 * u + 0] = (signed char)(int)rintf(qclip(fdivn(v.x, a, ra)));
    o.c[4 * u + 1] = (signed char)(int)rintf(qclip(fdivn(v.y, a, ra)));
    o.c[4 * u + 2] = (signed char)(int)rintf(qclip(fdivn(v.z, a, ra)));
    o.c[4 * u + 3] = (signed char)(int)rintf(qclip(fdivn(v.w, a, ra)));
  }
  *(uint4*)(out + 16 * (size_t)i) = o.u;
}

// ---------------- fused prep: quantize x, w_qkv, w_proj + exp table ----------------
__global__ __launch_bounds__(256)
void prep(const float* __restrict__ x, const float* __restrict__ wqkv,
          const float* __restrict__ wproj,
          signed char* __restrict__ xq, signed char* __restrict__ wqq,
          signed char* __restrict__ wpq, float* __restrict__ E2,
          const float* __restrict__ a_qkv_a, const float* __restrict__ a_qkv_w,
          const float* __restrict__ a_proj_w, const float* __restrict__ aattn) {
  const int b = blockIdx.x, t = threadIdx.x;
  if (b < 384) {
    int i = b * 256 + t;
    if (i < 98304) quant16_body(x, xq, a_qkv_a[0], i);
  } else if (b < 492) {
    int i = (b - 384) * 256 + t;
    if (i < 27648) quant16_body(wqkv, wqq, a_qkv_w[0], i);
  } else if (b < 528) {
    int i = (b - 492) * 256 + t;
    if (i < 9216) quant16_body(wproj, wpq, a_proj_w[0], i);
  } else {
    int i = (b - 528) * 256 + t;       // 0..65535
    float a = aattn[0];
    int vm = (i >> 8) - 128;
    int s = (i & 255) - 128;
    float m = a * (float)vm;
    E2[i] = expf(a * (float)s - m);    // same source expr as verified path
  }
}

// ---------------- QKV GEMM (i8 MFMA): [4096,384] @ [1152,384]^T ----------------
// 64x64 block tile, grid (64,18).  Wave (kw,nw): kw = K-half (192), nw = n-half
// (32 cols).  Exact int K-reduce through LDS (stride 33), epilogue on kw=0.
__global__ __launch_bounds__(256)
void gemm_qkv(const signed char* __restrict__ A, const signed char* __restrict__ W,
              signed char* __restrict__ qws, signed char* __restrict__ kws,
              signed char* __restrict__ vwsT,
              const float* __restrict__ aa, const float* __restrict__ aw,
              const float* __restrict__ aq, const float* __restrict__ ak,
              const float* __restrict__ av) {
  __shared__ int red[2 * 64 * 33];     // 16,896 B
  const int t = threadIdx.x;
  const int w = t >> 6, lane = t & 63;
  const int lm = lane & 15, quad = lane >> 4;
  const int kw = w >> 1, nw = w & 1;
  const int m0 = blockIdx.x * 64;
  const int n0 = blockIdx.y * 64 + nw * 32;
  i32x4 acc[4][2] = {};
#pragma unroll
  for (int kk = 0; kk < 3; ++kk) {
    int k0 = kw * 192 + kk * 64;
    i32x4 af[4], bf[2];
#pragma unroll
    for (int mt = 0; mt < 4; ++mt)
      af[mt] = *(const i32x4*)(A + (size_t)(m0 + mt * 16 + lm) * 384 + k0 + quad * 16);
#pragma unroll
    for (int nt = 0; nt < 2; ++nt)
      bf[nt] = *(const i32x4*)(W + (size_t)(n0 + nt * 16 + lm) * 384 + k0 + quad * 16);
#pragma unroll
    for (int mt = 0; mt < 4; ++mt)
#pragma unroll
      for (int nt = 0; nt < 2; ++nt)
        acc[mt][nt] = MFMA_I8(af[mt], bf[nt], acc[mt][nt]);
  }
  if (kw == 1) {
    int* rw = red + nw * 2112 + lane * 33;
#pragma unroll
    for (int mt = 0; mt < 4; ++mt)
#pragma unroll
      for (int nt = 0; nt < 2; ++nt)
#pragma unroll
        for (int r = 0; r < 4; ++r)
          rw[mt * 8 + nt * 4 + r] = acc[mt][nt][r];
  }
  __syncthreads();
  if (kw == 0) {
    const int* rw = red + nw * 2112 + lane * 33;
    const float sAB = aa[0] * aw[0];
    const float vaq = aq[0], vak = ak[0], vav = av[0];
    const float rq = 1.0f / vaq, rk = 1.0f / vak, rv = 1.0f / vav;
#pragma unroll
    for (int mt = 0; mt < 4; ++mt) {
#pragma unroll
      for (int nt = 0; nt < 2; ++nt) {
        int cg = n0 + nt * 16 + lm;
        int t3 = cg / 384;
        int rem = cg - t3 * 384;
        int h = rem >> 6, d = rem & 63;
#pragma unroll
        for (int r = 0; r < 4; ++r) {
          int m = m0 + mt * 16 + quad * 4 + r;
          int bb = m >> 11, nn = m & 2047;
          int bh = bb * 6 + h;
          int sum = acc[mt][nt][r] + rw[mt * 8 + nt * 4 + r];
          float val = (float)sum * sAB;
          if (t3 == 0) {
            qws[((size_t)(bh * 2048 + nn) << 6) + d] =
                (signed char)(int)rintf(qclip(fdivn(val, vaq, rq)));
          } else if (t3 == 1) {
            kws[((size_t)(bh * 2048 + nn) << 6) + d] =
                (signed char)(int)rintf(qclip(fdivn(val, vak, rk)));
          } else {
            vwsT[((size_t)((bh << 6) + d) << 11) + nn] =
                (signed char)(int)rintf(qclip(fdivn(val, vav, rv)));
          }
        }
      }
    }
  }
}

// ---------------- fully fused attention: S = qK^T -> softmax -> PV ----------------
// Block = 256 thr = 4 waves, 16 q-rows, one bh.
// B: scores tile via operand-swapped MFMA, packed-f32 requant, ds_write_b32.
// C: vals for all 4 rows read first; 4 interleaved max chains; ALL 16 E2
//    loads issued together into registers; then per-row LDS stage / gather /
//    ordered sum / packed translate (per-row op order unchanged -> exact).
// E: plain ds_read_b128 A-frags; 4-way K-split i8 GEMM, V from global.
// F: exact integer LDS reduce (aliases tile) + requant epilogue.
#define TROW 2064
__global__ __launch_bounds__(256, 4)
void attn_fused(const signed char* __restrict__ qws, const signed char* __restrict__ kws,
                const signed char* __restrict__ vwsT, const float* __restrict__ E2,
                signed char* __restrict__ ows,
                const float* __restrict__ aq, const float* __restrict__ ak,
                const float* __restrict__ aattn, const float* __restrict__ aattn2,
                const float* __restrict__ av, const float* __restrict__ apa) {
  __shared__ signed char tileS[16 * TROW];   // 33,024 B (int reduce aliases)
  __shared__ float EfS[4 * 257];             //  4,112 B wave-private slots
  const int t = threadIdx.x;
  const int w = t >> 6, lane = t & 63;
  const int lm = lane & 15, quad = lane >> 4;
  const int i0 = blockIdx.x * 16;
  const int bh = blockIdx.y;

  const signed char* Qb = qws + ((size_t)bh << 17);
  const signed char* Kb = kws + ((size_t)bh << 17);

  // ---- phase B: scores tile.  bq = this block's 16 q-rows (B operand).
  i32x4 bq = *(const i32x4*)(Qb + ((size_t)(i0 + lm) << 6) + quad * 16);
  const float sc = aq[0] * ak[0] * 0.125f;
  const float ia = aattn[0];
  const float ria = 1.0f / ia;
  const f32x2 ia2v = {ia, ia}, ria2v = {ria, ria}, sc2v = {sc, sc};
#pragma unroll 4
  for (int ct = 0; ct < 32; ++ct) {
    int col0 = (w << 9) + ct * 16;
    i32x4 akf = *(const i32x4*)(Kb + ((size_t)(col0 + lm) << 6) + quad * 16);
    i32x4 z = {};
    i32x4 acc = MFMA_I8(akf, bq, z);
    f32x2 sv01 = {(float)acc[0], (float)acc[1]};
    f32x2 sv23 = {(float)acc[2], (float)acc[3]};
    f32x2 q01 = fdivn2(sv01 * sc2v, ia2v, ria2v);
    f32x2 q23 = fdivn2(sv23 * sc2v, ia2v, ria2v);
    union { unsigned int u; signed char c[4]; } pk;
    pk.c[0] = (signed char)(int)rintf(qclip(q01.x));
    pk.c[1] = (signed char)(int)rintf(qclip(q01.y));
    pk.c[2] = (signed char)(int)rintf(qclip(q23.x));
    pk.c[3] = (signed char)(int)rintf(qclip(q23.y));
    *(unsigned int*)(tileS + lm * TROW + col0 + quad * 4) = pk.u;
  }
  __syncthreads();

  // ---- phase C: stats + in-place S->P translation (wave w owns rows 4w..4w+3)
  const float a2 = aattn2[0];
  const float ra2 = 1.0f / a2;
  const f32x2 a22v = {a2, a2}, ra22v = {ra2, ra2};
  float* Efw = EfS + w * 257;                // wave-private slot

  // C1: read vals for all 4 rows (independent LDS loads, all in flight)
  char4 vals4[4][8];
#pragma unroll
  for (int rr = 0; rr < 4; ++rr) {
    const char4* prow = (const char4*)(tileS + (w * 4 + rr) * TROW);
#pragma unroll
    for (int u = 0; u < 8; ++u) vals4[rr][u] = prow[lane + (u << 6)];
  }
  // C2: interleaved max chains (per-row op order unchanged)
  int vmax4[4];
#pragma unroll
  for (int rr = 0; rr < 4; ++rr) {
    int vm = -129;
#pragma unroll
    for (int u = 0; u < 8; ++u) {
      vm = max(vm, (int)vals4[rr][u].x);
      vm = max(vm, (int)vals4[rr][u].y);
      vm = max(vm, (int)vals4[rr][u].z);
      vm = max(vm, (int)vals4[rr][u].w);
    }
    vmax4[rr] = vm;
  }
#pragma unroll
  for (int off = 32; off > 0; off >>= 1) {
#pragma unroll
    for (int rr = 0; rr < 4; ++rr)
      vmax4[rr] = max(vmax4[rr], __shfl_xor(vmax4[rr], off, 64));
  }
  // C3: issue ALL E2 slice loads together (16 independent global loads)
  float e2p[4][4];
#pragma unroll
  for (int rr = 0; rr < 4; ++rr)
#pragma unroll
    for (int u = 0; u < 4; ++u)
      e2p[rr][u] = E2[((vmax4[rr] + 128) << 8) + u * 64 + lane];
  // C4: per-row stage / gather / ordered sum / translate
#pragma unroll
  for (int rr = 0; rr < 4; ++rr) {
    const int row = w * 4 + rr;
    char4* prow = (char4*)(tileS + row * TROW);
#pragma unroll
    for (int u = 0; u < 4; ++u)
      Efw[u * 64 + lane] = e2p[rr][u];
    const float* Er = Efw + 128;
    float ge[8][4];
    float l = 0.0f;
#pragma unroll
    for (int u = 0; u < 8; ++u) {
      ge[u][0] = Er[(int)vals4[rr][u].x];
      ge[u][1] = Er[(int)vals4[rr][u].y];
      ge[u][2] = Er[(int)vals4[rr][u].z];
      ge[u][3] = Er[(int)vals4[rr][u].w];
      l += ge[u][0];
      l += ge[u][1];
      l += ge[u][2];
      l += ge[u][3];
    }
#pragma unroll
    for (int off = 32; off > 0; off >>= 1)
      l += __shfl_xor(l, off, 64);
    const float rl = 1.0f / l;
    const f32x2 l2v = {l, l}, rl2v = {rl, rl};
#pragma unroll
    for (int u = 0; u < 8; ++u) {
      f32x2 g01 = {ge[u][0], ge[u][1]};
      f32x2 g23 = {ge[u][2], ge[u][3]};
      f32x2 t01 = fdivn2(fdivn2(g01, l2v, rl2v), a22v, ra22v);
      f32x2 t23 = fdivn2(fdivn2(g23, l2v, rl2v), a22v, ra22v);
      union { unsigned int ui; signed char c[4]; } pk;
      pk.c[0] = (signed char)(int)rintf(qclip(t01.x));
      pk.c[1] = (signed char)(int)rintf(qclip(t01.y));
      pk.c[2] = (signed char)(int)rintf(qclip(t23.x));
      pk.c[3] = (signed char)(int)rintf(qclip(t23.y));
      *(unsigned int*)(prow + lane + (u << 6)) = pk.ui;
    }
  }
  __syncthreads();

  // ---- phase E: plain A-frag reads + K-split GEMM (wave w: K quarter)
  i32x4 areg[8];
  {
    const signed char* srow = tileS + lm * TROW + (w << 9) + quad * 16;
#pragma unroll
    for (int js = 0; js < 8; ++js)
      areg[js] = *(const i32x4*)(srow + js * 64);
  }
  const signed char* Vb = vwsT + ((size_t)bh << 17) + (w << 9);
  i32x4 acc[4] = {};
#pragma unroll
  for (int js = 0; js < 8; ++js) {
    int j0 = js * 64;
    i32x4 bf[4];
#pragma unroll
    for (int nt = 0; nt < 4; ++nt)
      bf[nt] = *(const i32x4*)(Vb + ((size_t)(nt * 16 + lm) << 11) + j0 + quad * 16);
#pragma unroll
    for (int nt = 0; nt < 4; ++nt)
      acc[nt] = MFMA_I8(areg[js], bf[nt], acc[nt]);
  }

  // ---- phase F: exact integer reduce (aliases tile) + epilogue
  int* red = (int*)tileS;
  __syncthreads();
  if (w > 0) {
    int* rw = red + (w - 1) * 1088 + lane * 17;
#pragma unroll
    for (int nt = 0; nt < 4; ++nt)
#pragma unroll
      for (int r = 0; r < 4; ++r)
        rw[nt * 4 + r] = acc[nt][r];
  }
  __syncthreads();
  if (w == 0) {
    const float so = a2 * av[0];
    const float ipa = apa[0];
    const float ripa = 1.0f / ipa;
    int bb = bh / 6, h = bh % 6;
#pragma unroll
    for (int nt = 0; nt < 4; ++nt) {
      int d = nt * 16 + lm;
#pragma unroll
      for (int r = 0; r < 4; ++r) {
        int s = acc[nt][r] + red[lane * 17 + nt * 4 + r]
              + red[1088 + lane * 17 + nt * 4 + r]
              + red[2176 + lane * 17 + nt * 4 + r];
        int i = i0 + quad * 4 + r;
        ows[(size_t)((bb << 11) + i) * 384 + (h << 6) + d] =
            (signed char)(int)rintf(qclip(fdivn((float)s * so, ipa, ripa)));
      }
    }
  }
}

// ---------------- proj (i8 MFMA): [4096,384] @ [384,384]^T * s + bias ----------------
// 64x64 block tile, grid (64,6).  Wave (kw,nw): kw = K-half (192), nw = n-half
// (32 cols).  Exact int K-reduce through LDS (stride 33), epilogue on kw=0.
__global__ __launch_bounds__(256)
void gemm_proj(const signed char* __restrict__ A, const signed char* __restrict__ W,
               const float* __restrict__ bias, float* __restrict__ out,
               const float* __restrict__ apa, const float* __restrict__ apw) {
  __shared__ int red[2 * 64 * 33];     // 16,896 B
  const int t = threadIdx.x;
  const int w = t >> 6, lane = t & 63;
  const int lm = lane & 15, quad = lane >> 4;
  const int kw = w >> 1, nw = w & 1;
  const int m0 = blockIdx.x * 64;
  const int n0 = blockIdx.y * 64 + nw * 32;
  i32x4 acc[4][2] = {};
#pragma unroll
  for (int kk = 0; kk < 3; ++kk) {
    int k0 = kw * 192 + kk * 64;
    i32x4 af[4], bf[2];
#pragma unroll
    for (int mt = 0; mt < 4; ++mt)
      af[mt] = *(const i32x4*)(A + (size_t)(m0 + mt * 16 + lm) * 384 + k0 + quad * 16);
#pragma unroll
    for (int nt = 0; nt < 2; ++nt)
      bf[nt] = *(const i32x4*)(W + (size_t)(n0 + nt * 16 + lm) * 384 + k0 + quad * 16);
#pragma unroll
    for (int mt = 0; mt < 4; ++mt)
#pragma unroll
      for (int nt = 0; nt < 2; ++nt)
        acc[mt][nt] = MFMA_I8(af[mt], bf[nt], acc[mt][nt]);
  }
  if (kw == 1) {
    int* rw = red + nw * 2112 + lane * 33;
#pragma unroll
    for (int mt = 0; mt < 4; ++mt)
#pragma unroll
      for (int nt = 0; nt < 2; ++nt)
#pragma unroll
        for (int r = 0; r < 4; ++r)
          rw[mt * 8 + nt * 4 + r] = acc[mt][nt][r];
  }
  __syncthreads();
  if (kw == 0) {
    const int* rw = red + nw * 2112 + lane * 33;
    const float sAB = apa[0] * apw[0];
#pragma unroll
    for (int mt = 0; mt < 4; ++mt) {
#pragma unroll
      for (int nt = 0; nt < 2; ++nt) {
        int cg = n0 + nt * 16 + lm;
#pragma unroll
        for (int r = 0; r < 4; ++r) {
          int m = m0 + mt * 16 + quad * 4 + r;
          int sum = acc[mt][nt][r] + rw[mt * 8 + nt * 4 + r];
          out[(size_t)m * 384 + cg] = (float)sum * sAB + bias[cg];
        }
      }
    }
  }
}

extern "C" void kernel_launch(void* const* d_in, const int* in_sizes, int n_in,
                              void* d_out, int out_size, void* d_ws, size_t ws_size,
                              hipStream_t stream) {
  const float* x        = (const float*)d_in[0];
  const float* w_qkv    = (const float*)d_in[1];
  const float* w_proj   = (const float*)d_in[2];
  const float* b_proj   = (const float*)d_in[3];
  const float* a_qkv_w  = (const float*)d_in[4];
  const float* a_qkv_a  = (const float*)d_in[5];
  const float* a_proj_w = (const float*)d_in[6];
  const float* a_proj_a = (const float*)d_in[7];
  const float* a_q      = (const float*)d_in[8];
  const float* a_k      = (const float*)d_in[9];
  const float* a_v      = (const float*)d_in[10];
  const float* a_attn   = (const float*)d_in[11];
  const float* a_attn2  = (const float*)d_in[12];

  char* wsb = (char*)d_ws;
  signed char* xq   = (signed char*)(wsb + 0);        // 4096*384      = 1,572,864 B
  signed char* wqq  = (signed char*)(wsb + 1572864);  // 1152*384      =   442,368 B
  signed char* wpq  = (signed char*)(wsb + 2015232);  //  384*384      =   147,456 B
  signed char* qws  = (signed char*)(wsb + 2162688);  // 12*2048*64    = 1,572,864 B
  signed char* kws  = (signed char*)(wsb + 3735552);  // same
  signed char* vwsT = (signed char*)(wsb + 5308416);  // same, [bh,d,n]
  signed char* ows  = (signed char*)(wsb + 6881280);  // 4096*384      = 1,572,864 B
  float*       E2   = (float*)(wsb + 8454144);        // 256*256 f32   =   262,144 B
  // total ws usage: 8,716,288 bytes

  prep<<<784, 256, 0, stream>>>(x, w_qkv, w_proj, xq, wqq, wpq, E2,
                                a_qkv_a, a_qkv_w, a_proj_w, a_attn);
  gemm_qkv<<<dim3(64, 18), 256, 0, stream>>>(xq, wqq, qws, kws, vwsT,
                                             a_qkv_a, a_qkv_w, a_q, a_k, a_v);
  attn_fused<<<dim3(128, 12), 256, 0, stream>>>(qws, kws, vwsT, E2, ows,
                                                a_q, a_k, a_attn, a_attn2,
                                                a_v, a_proj_a);
  gemm_proj<<<dim3(64, 6), 256, 0, stream>>>(ows, wpq, b_proj, (float*)d_out,
                                             a_proj_a, a_proj_w);
}

// Round 11
// 152.024 us; speedup vs baseline: 1.0369x; 1.0369x over previous
//
#include <hip/hip_runtime.h>
#include <math.h>

// B=2, N=2048, C=384, H=6, D=64.  All quantized tensors hold INTEGER values
// (round(clip(x/a))) stored as int8; alpha scales are factored into epilogues.
// All GEMMs use v_mfma_i32_16x16x64_i8 (i32 accumulation exact; sums < 2^24
// so the (float) conversion is bit-exact).
//
// Round 11: revert of round 10's phase-C ILP restructure (it spilled:
// WRITE_SIZE 1.5->43 MB scratch traffic, attn 53.6->64 us).  Phase C is the
// verified round-9 serial per-row loop (register working set = one row).
// Kept from round 10 (spill-free, bit-identical): qclip via v_med3_f32 and
// the gemm_proj K-split retile.

typedef int i32x4 __attribute__((ext_vector_type(4)));
typedef float f32x2 __attribute__((ext_vector_type(2)));

#define MFMA_I8(a, b, c) __builtin_amdgcn_mfma_i32_16x16x64_i8(a, b, c, 0, 0, 0)

__device__ __forceinline__ float qclip(float s) {
  return __builtin_amdgcn_fmed3f(s, -128.0f, 127.0f);  // clamp, bit-identical
}

// Markstein divide: with rc = RN(1/c) (IEEE), result == RN(x/c) for all
// normal inputs -> bit-identical to the / operator.
__device__ __forceinline__ float fdivn(float x, float c, float rc) {
  float q0 = x * rc;
  float e = fmaf(-c, q0, x);
  return fmaf(e, rc, q0);
}

// Packed pair version: identical per-lane ops/order -> bit-identical.
__device__ __forceinline__ f32x2 fdivn2(f32x2 x, f32x2 c, f32x2 rc) {
  f32x2 q0 = x * rc;
  f32x2 e = __builtin_elementwise_fma(-c, q0, x);
  return __builtin_elementwise_fma(e, rc, q0);
}

__device__ __forceinline__ void quant16_body(const float* __restrict__ in,
                                             signed char* __restrict__ out,
                                             float a, int i) {
  const float ra = 1.0f / a;
  const float4* p = (const float4*)in + 4 * (size_t)i;
  union { uint4 u; signed char c[16]; } o;
#pragma unroll
  for (int u = 0; u < 4; ++u) {
    float4 v = p[u];
    o.c[4 * u + 0] = (signed char)(int)rintf(qclip(fdivn(v.x, a, ra)));
    o.c[4 * u + 1] = (signed char)(int)rintf(qclip(fdivn(v.y, a, ra)));
    o.c[4 * u + 2] = (signed char)(int)rintf(qclip(fdivn(v.z, a, ra)));
    o.c[4 * u + 3] = (signed char)(int)rintf(qclip(fdivn(v.w, a, ra)));
  }
  *(uint4*)(out + 16 * (size_t)i) = o.u;
}

// ---------------- fused prep: quantize x, w_qkv, w_proj + exp table ----------------
__global__ __launch_bounds__(256)
void prep(const float* __restrict__ x, const float* __restrict__ wqkv,
          const float* __restrict__ wproj,
          signed char* __restrict__ xq, signed char* __restrict__ wqq,
          signed char* __restrict__ wpq, float* __restrict__ E2,
          const float* __restrict__ a_qkv_a, const float* __restrict__ a_qkv_w,
          const float* __restrict__ a_proj_w, const float* __restrict__ aattn) {
  const int b = blockIdx.x, t = threadIdx.x;
  if (b < 384) {
    int i = b * 256 + t;
    if (i < 98304) quant16_body(x, xq, a_qkv_a[0], i);
  } else if (b < 492) {
    int i = (b - 384) * 256 + t;
    if (i < 27648) quant16_body(wqkv, wqq, a_qkv_w[0], i);
  } else if (b < 528) {
    int i = (b - 492) * 256 + t;
    if (i < 9216) quant16_body(wproj, wpq, a_proj_w[0], i);
  } else {
    int i = (b - 528) * 256 + t;       // 0..65535
    float a = aattn[0];
    int vm = (i >> 8) - 128;
    int s = (i & 255) - 128;
    float m = a * (float)vm;
    E2[i] = expf(a * (float)s - m);    // same source expr as verified path
  }
}

// ---------------- QKV GEMM (i8 MFMA): [4096,384] @ [1152,384]^T ----------------
// 64x64 block tile, grid (64,18).  Wave (kw,nw): kw = K-half (192), nw = n-half
// (32 cols).  Exact int K-reduce through LDS (stride 33), epilogue on kw=0.
__global__ __launch_bounds__(256)
void gemm_qkv(const signed char* __restrict__ A, const signed char* __restrict__ W,
              signed char* __restrict__ qws, signed char* __restrict__ kws,
              signed char* __restrict__ vwsT,
              const float* __restrict__ aa, const float* __restrict__ aw,
              const float* __restrict__ aq, const float* __restrict__ ak,
              const float* __restrict__ av) {
  __shared__ int red[2 * 64 * 33];     // 16,896 B
  const int t = threadIdx.x;
  const int w = t >> 6, lane = t & 63;
  const int lm = lane & 15, quad = lane >> 4;
  const int kw = w >> 1, nw = w & 1;
  const int m0 = blockIdx.x * 64;
  const int n0 = blockIdx.y * 64 + nw * 32;
  i32x4 acc[4][2] = {};
#pragma unroll
  for (int kk = 0; kk < 3; ++kk) {
    int k0 = kw * 192 + kk * 64;
    i32x4 af[4], bf[2];
#pragma unroll
    for (int mt = 0; mt < 4; ++mt)
      af[mt] = *(const i32x4*)(A + (size_t)(m0 + mt * 16 + lm) * 384 + k0 + quad * 16);
#pragma unroll
    for (int nt = 0; nt < 2; ++nt)
      bf[nt] = *(const i32x4*)(W + (size_t)(n0 + nt * 16 + lm) * 384 + k0 + quad * 16);
#pragma unroll
    for (int mt = 0; mt < 4; ++mt)
#pragma unroll
      for (int nt = 0; nt < 2; ++nt)
        acc[mt][nt] = MFMA_I8(af[mt], bf[nt], acc[mt][nt]);
  }
  if (kw == 1) {
    int* rw = red + nw * 2112 + lane * 33;
#pragma unroll
    for (int mt = 0; mt < 4; ++mt)
#pragma unroll
      for (int nt = 0; nt < 2; ++nt)
#pragma unroll
        for (int r = 0; r < 4; ++r)
          rw[mt * 8 + nt * 4 + r] = acc[mt][nt][r];
  }
  __syncthreads();
  if (kw == 0) {
    const int* rw = red + nw * 2112 + lane * 33;
    const float sAB = aa[0] * aw[0];
    const float vaq = aq[0], vak = ak[0], vav = av[0];
    const float rq = 1.0f / vaq, rk = 1.0f / vak, rv = 1.0f / vav;
#pragma unroll
    for (int mt = 0; mt < 4; ++mt) {
#pragma unroll
      for (int nt = 0; nt < 2; ++nt) {
        int cg = n0 + nt * 16 + lm;
        int t3 = cg / 384;
        int rem = cg - t3 * 384;
        int h = rem >> 6, d = rem & 63;
#pragma unroll
        for (int r = 0; r < 4; ++r) {
          int m = m0 + mt * 16 + quad * 4 + r;
          int bb = m >> 11, nn = m & 2047;
          int bh = bb * 6 + h;
          int sum = acc[mt][nt][r] + rw[mt * 8 + nt * 4 + r];
          float val = (float)sum * sAB;
          if (t3 == 0) {
            qws[((size_t)(bh * 2048 + nn) << 6) + d] =
                (signed char)(int)rintf(qclip(fdivn(val, vaq, rq)));
          } else if (t3 == 1) {
            kws[((size_t)(bh * 2048 + nn) << 6) + d] =
                (signed char)(int)rintf(qclip(fdivn(val, vak, rk)));
          } else {
            vwsT[((size_t)((bh << 6) + d) << 11) + nn] =
                (signed char)(int)rintf(qclip(fdivn(val, vav, rv)));
          }
        }
      }
    }
  }
}

// ---------------- fully fused attention: S = qK^T -> softmax -> PV ----------------
// Block = 256 thr = 4 waves, 16 q-rows, one bh.
// B: scores tile via operand-swapped MFMA, packed-f32 requant, ds_write_b32.
// C: per-row stats (verified round-9 serial loop: register set = one row);
//    Ef slice staged to a WAVE-PRIVATE LDS slot; gathered ef floats reused
//    for packed-f32 in-place translation (Markstein, bit-exact).
// E: plain ds_read_b128 A-frags; 4-way K-split i8 GEMM, V from global.
// F: exact integer LDS reduce (aliases tile) + requant epilogue.
#define TROW 2064
__global__ __launch_bounds__(256)
void attn_fused(const signed char* __restrict__ qws, const signed char* __restrict__ kws,
                const signed char* __restrict__ vwsT, const float* __restrict__ E2,
                signed char* __restrict__ ows,
                const float* __restrict__ aq, const float* __restrict__ ak,
                const float* __restrict__ aattn, const float* __restrict__ aattn2,
                const float* __restrict__ av, const float* __restrict__ apa) {
  __shared__ signed char tileS[16 * TROW];   // 33,024 B (int reduce aliases)
  __shared__ float EfS[4 * 257];             //  4,112 B wave-private slots
  const int t = threadIdx.x;
  const int w = t >> 6, lane = t & 63;
  const int lm = lane & 15, quad = lane >> 4;
  const int i0 = blockIdx.x * 16;
  const int bh = blockIdx.y;

  const signed char* Qb = qws + ((size_t)bh << 17);
  const signed char* Kb = kws + ((size_t)bh << 17);

  // ---- phase B: scores tile.  bq = this block's 16 q-rows (B operand).
  i32x4 bq = *(const i32x4*)(Qb + ((size_t)(i0 + lm) << 6) + quad * 16);
  const float sc = aq[0] * ak[0] * 0.125f;
  const float ia = aattn[0];
  const float ria = 1.0f / ia;
  const f32x2 ia2v = {ia, ia}, ria2v = {ria, ria}, sc2v = {sc, sc};
#pragma unroll 4
  for (int ct = 0; ct < 32; ++ct) {
    int col0 = (w << 9) + ct * 16;
    i32x4 akf = *(const i32x4*)(Kb + ((size_t)(col0 + lm) << 6) + quad * 16);
    i32x4 z = {};
    i32x4 acc = MFMA_I8(akf, bq, z);
    f32x2 sv01 = {(float)acc[0], (float)acc[1]};
    f32x2 sv23 = {(float)acc[2], (float)acc[3]};
    f32x2 q01 = fdivn2(sv01 * sc2v, ia2v, ria2v);
    f32x2 q23 = fdivn2(sv23 * sc2v, ia2v, ria2v);
    union { unsigned int u; signed char c[4]; } pk;
    pk.c[0] = (signed char)(int)rintf(qclip(q01.x));
    pk.c[1] = (signed char)(int)rintf(qclip(q01.y));
    pk.c[2] = (signed char)(int)rintf(qclip(q23.x));
    pk.c[3] = (signed char)(int)rintf(qclip(q23.y));
    *(unsigned int*)(tileS + lm * TROW + col0 + quad * 4) = pk.u;
  }
  __syncthreads();

  // ---- phase C: stats + in-place S->P translation (wave w owns rows 4w..4w+3)
  const float a2 = aattn2[0];
  const float ra2 = 1.0f / a2;
  const f32x2 a22v = {a2, a2}, ra22v = {ra2, ra2};
  float* Efw = EfS + w * 257;                // wave-private slot
#pragma unroll
  for (int rr = 0; rr < 4; ++rr) {
    const int row = w * 4 + rr;
    char4* prow = (char4*)(tileS + row * TROW);
    char4 vals[8];
    int vmax = -129;
#pragma unroll
    for (int u = 0; u < 8; ++u) {
      vals[u] = prow[lane + (u << 6)];
      vmax = max(vmax, (int)vals[u].x);
      vmax = max(vmax, (int)vals[u].y);
      vmax = max(vmax, (int)vals[u].z);
      vmax = max(vmax, (int)vals[u].w);
    }
#pragma unroll
    for (int off = 32; off > 0; off >>= 1)
      vmax = max(vmax, __shfl_xor(vmax, off, 64));
    // stage this row's exp slice into the wave slot: lane holds u*64+lane
#pragma unroll
    for (int u = 0; u < 4; ++u)
      Efw[u * 64 + lane] = E2[((vmax + 128) << 8) + u * 64 + lane];
    const float* Er = Efw + 128;
    // gather ef for every element (kept for translation) and sum in the
    // verified order (scalar dependent chain -> bit-exact l)
    float ge[8][4];
    float l = 0.0f;
#pragma unroll
    for (int u = 0; u < 8; ++u) {
      ge[u][0] = Er[(int)vals[u].x];
      ge[u][1] = Er[(int)vals[u].y];
      ge[u][2] = Er[(int)vals[u].z];
      ge[u][3] = Er[(int)vals[u].w];
      l += ge[u][0];
      l += ge[u][1];
      l += ge[u][2];
      l += ge[u][3];
    }
#pragma unroll
    for (int off = 32; off > 0; off >>= 1)
      l += __shfl_xor(l, off, 64);
    // translate: p = rint(clip(ef/l/a2)), exact Markstein, packed pairs
    const float rl = 1.0f / l;
    const f32x2 l2v = {l, l}, rl2v = {rl, rl};
#pragma unroll
    for (int u = 0; u < 8; ++u) {
      f32x2 g01 = {ge[u][0], ge[u][1]};
      f32x2 g23 = {ge[u][2], ge[u][3]};
      f32x2 t01 = fdivn2(fdivn2(g01, l2v, rl2v), a22v, ra22v);
      f32x2 t23 = fdivn2(fdivn2(g23, l2v, rl2v), a22v, ra22v);
      union { unsigned int ui; signed char c[4]; } pk;
      pk.c[0] = (signed char)(int)rintf(qclip(t01.x));
      pk.c[1] = (signed char)(int)rintf(qclip(t01.y));
      pk.c[2] = (signed char)(int)rintf(qclip(t23.x));
      pk.c[3] = (signed char)(int)rintf(qclip(t23.y));
      *(unsigned int*)(prow + lane + (u << 6)) = pk.ui;
    }
  }
  __syncthreads();

  // ---- phase E: plain A-frag reads + K-split GEMM (wave w: K quarter)
  i32x4 areg[8];
  {
    const signed char* srow = tileS + lm * TROW + (w << 9) + quad * 16;
#pragma unroll
    for (int js = 0; js < 8; ++js)
      areg[js] = *(const i32x4*)(srow + js * 64);
  }
  const signed char* Vb = vwsT + ((size_t)bh << 17) + (w << 9);
  i32x4 acc[4] = {};
#pragma unroll
  for (int js = 0; js < 8; ++js) {
    int j0 = js * 64;
    i32x4 bf[4];
#pragma unroll
    for (int nt = 0; nt < 4; ++nt)
      bf[nt] = *(const i32x4*)(Vb + ((size_t)(nt * 16 + lm) << 11) + j0 + quad * 16);
#pragma unroll
    for (int nt = 0; nt < 4; ++nt)
      acc[nt] = MFMA_I8(areg[js], bf[nt], acc[nt]);
  }

  // ---- phase F: exact integer reduce (aliases tile) + epilogue
  int* red = (int*)tileS;
  __syncthreads();
  if (w > 0) {
    int* rw = red + (w - 1) * 1088 + lane * 17;
#pragma unroll
    for (int nt = 0; nt < 4; ++nt)
#pragma unroll
      for (int r = 0; r < 4; ++r)
        rw[nt * 4 + r] = acc[nt][r];
  }
  __syncthreads();
  if (w == 0) {
    const float so = a2 * av[0];
    const float ipa = apa[0];
    const float ripa = 1.0f / ipa;
    int bb = bh / 6, h = bh % 6;
#pragma unroll
    for (int nt = 0; nt < 4; ++nt) {
      int d = nt * 16 + lm;
#pragma unroll
      for (int r = 0; r < 4; ++r) {
        int s = acc[nt][r] + red[lane * 17 + nt * 4 + r]
              + red[1088 + lane * 17 + nt * 4 + r]
              + red[2176 + lane * 17 + nt * 4 + r];
        int i = i0 + quad * 4 + r;
        ows[(size_t)((bb << 11) + i) * 384 + (h << 6) + d] =
            (signed char)(int)rintf(qclip(fdivn((float)s * so, ipa, ripa)));
      }
    }
  }
}

// ---------------- proj (i8 MFMA): [4096,384] @ [384,384]^T * s + bias ----------------
// 64x64 block tile, grid (64,6).  Wave (kw,nw): kw = K-half (192), nw = n-half
// (32 cols).  Exact int K-reduce through LDS (stride 33), epilogue on kw=0.
__global__ __launch_bounds__(256)
void gemm_proj(const signed char* __restrict__ A, const signed char* __restrict__ W,
               const float* __restrict__ bias, float* __restrict__ out,
               const float* __restrict__ apa, const float* __restrict__ apw) {
  __shared__ int red[2 * 64 * 33];     // 16,896 B
  const int t = threadIdx.x;
  const int w = t >> 6, lane = t & 63;
  const int lm = lane & 15, quad = lane >> 4;
  const int kw = w >> 1, nw = w & 1;
  const int m0 = blockIdx.x * 64;
  const int n0 = blockIdx.y * 64 + nw * 32;
  i32x4 acc[4][2] = {};
#pragma unroll
  for (int kk = 0; kk < 3; ++kk) {
    int k0 = kw * 192 + kk * 64;
    i32x4 af[4], bf[2];
#pragma unroll
    for (int mt = 0; mt < 4; ++mt)
      af[mt] = *(const i32x4*)(A + (size_t)(m0 + mt * 16 + lm) * 384 + k0 + quad * 16);
#pragma unroll
    for (int nt = 0; nt < 2; ++nt)
      bf[nt] = *(const i32x4*)(W + (size_t)(n0 + nt * 16 + lm) * 384 + k0 + quad * 16);
#pragma unroll
    for (int mt = 0; mt < 4; ++mt)
#pragma unroll
      for (int nt = 0; nt < 2; ++nt)
        acc[mt][nt] = MFMA_I8(af[mt], bf[nt], acc[mt][nt]);
  }
  if (kw == 1) {
    int* rw = red + nw * 2112 + lane * 33;
#pragma unroll
    for (int mt = 0; mt < 4; ++mt)
#pragma unroll
      for (int nt = 0; nt < 2; ++nt)
#pragma unroll
        for (int r = 0; r < 4; ++r)
          rw[mt * 8 + nt * 4 + r] = acc[mt][nt][r];
  }
  __syncthreads();
  if (kw == 0) {
    const int* rw = red + nw * 2112 + lane * 33;
    const float sAB = apa[0] * apw[0];
#pragma unroll
    for (int mt = 0; mt < 4; ++mt) {
#pragma unroll
      for (int nt = 0; nt < 2; ++nt) {
        int cg = n0 + nt * 16 + lm;
#pragma unroll
        for (int r = 0; r < 4; ++r) {
          int m = m0 + mt * 16 + quad * 4 + r;
          int sum = acc[mt][nt][r] + rw[mt * 8 + nt * 4 + r];
          out[(size_t)m * 384 + cg] = (float)sum * sAB + bias[cg];
        }
      }
    }
  }
}

extern "C" void kernel_launch(void* const* d_in, const int* in_sizes, int n_in,
                              void* d_out, int out_size, void* d_ws, size_t ws_size,
                              hipStream_t stream) {
  const float* x        = (const float*)d_in[0];
  const float* w_qkv    = (const float*)d_in[1];
  const float* w_proj   = (const float*)d_in[2];
  const float* b_proj   = (const float*)d_in[3];
  const float* a_qkv_w  = (const float*)d_in[4];
  const float* a_qkv_a  = (const float*)d_in[5];
  const float* a_proj_w = (const float*)d_in[6];
  const float* a_proj_a = (const float*)d_in[7];
  const float* a_q      = (const float*)d_in[8];
  const float* a_k      = (const float*)d_in[9];
  const float* a_v      = (const float*)d_in[10];
  const float* a_attn   = (const float*)d_in[11];
  const float* a_attn2  = (const float*)d_in[12];

  char* wsb = (char*)d_ws;
  signed char* xq   = (signed char*)(wsb + 0);        // 4096*384      = 1,572,864 B
  signed char* wqq  = (signed char*)(wsb + 1572864);  // 1152*384      =   442,368 B
  signed char* wpq  = (signed char*)(wsb + 2015232);  //  384*384      =   147,456 B
  signed char* qws  = (signed char*)(wsb + 2162688);  // 12*2048*64    = 1,572,864 B
  signed char* kws  = (signed char*)(wsb + 3735552);  // same
  signed char* vwsT = (signed char*)(wsb + 5308416);  // same, [bh,d,n]
  signed char* ows  = (signed char*)(wsb + 6881280);  // 4096*384      = 1,572,864 B
  float*       E2   = (float*)(wsb + 8454144);        // 256*256 f32   =   262,144 B
  // total ws usage: 8,716,288 bytes

  prep<<<784, 256, 0, stream>>>(x, w_qkv, w_proj, xq, wqq, wpq, E2,
                                a_qkv_a, a_qkv_w, a_proj_w, a_attn);
  gemm_qkv<<<dim3(64, 18), 256, 0, stream>>>(xq, wqq, qws, kws, vwsT,
                                             a_qkv_a, a_qkv_w, a_q, a_k, a_v);
  attn_fused<<<dim3(128, 12), 256, 0, stream>>>(qws, kws, vwsT, E2, ows,
                                                a_q, a_k, a_attn, a_attn2,
                                                a_v, a_proj_a);
  gemm_proj<<<dim3(64, 6), 256, 0, stream>>>(ows, wpq, b_proj, (float*)d_out,
                                             a_proj_a, a_proj_w);
}